// Round 3
// 1143.779 us; speedup vs baseline: 2.3132x; 2.3132x over previous
//
#include <hip/hip_runtime.h>
#include <hip/hip_bf16.h>
#include <math.h>

#define B_DIM 8
#define C_DIM 256
#define N_DIM 2048
#define CQ 64

#define TM 64
#define TN 64
#define TK 16

#define PV_BN 64
#define PV_BK 64

using short8 = __attribute__((ext_vector_type(8))) short;
using f32x4 = __attribute__((ext_vector_type(4))) float;

__device__ __forceinline__ unsigned short f2bf(float x) {
  union { float f; unsigned int u; } c; c.f = x;
  unsigned int r = c.u + 0x7fffu + ((c.u >> 16) & 1u);
  return (unsigned short)(r >> 16);
}
__device__ __forceinline__ float bf2f(unsigned short u) {
  union { unsigned int ui; float f; } c; c.ui = ((unsigned int)u) << 16;
  return c.f;
}

// pos[b,c,n] = sum_i w[c,i]*xyz[b,n,i]
__global__ void pos_kernel(const float* __restrict__ w, const float* __restrict__ xyz,
                           float* __restrict__ pos) {
  int n = blockIdx.x * blockDim.x + threadIdx.x;
  int c = blockIdx.y;
  int b = blockIdx.z;
  const float* xp = xyz + ((long long)b * N_DIM + n) * 3;
  pos[((long long)b * C_DIM + c) * N_DIM + n] =
      w[c * 3 + 0] * xp[0] + w[c * 3 + 1] * xp[1] + w[c * 3 + 2] * xp[2];
}

// Y[b,m,n] = epi( sum_k W[m,k] * (X[b,k,n] + Xadd[b,k,n]) )
// epi: +bias[m]; optional BN+ReLU; optional +Res. If Ybf != nullptr, write bf16 to Ybf
// instead of fp32 to Y.
__global__ void gemm_wx(const float* __restrict__ W,
                        const float* __restrict__ X, long long sxB,
                        const float* __restrict__ Xadd, long long saB,
                        const float* __restrict__ bias,
                        const float* __restrict__ bng, const float* __restrict__ bnb,
                        const float* __restrict__ bnm, const float* __restrict__ bnv,
                        const float* __restrict__ Res, long long srB,
                        float* __restrict__ Y, unsigned short* __restrict__ Ybf,
                        long long syB, int M, int K) {
  const int N = N_DIM;
  int b = blockIdx.z;
  int m0 = blockIdx.y * TM;
  int n0 = blockIdx.x * TN;
  int t = threadIdx.x;
  int tx = t & 15, ty = t >> 4;
  __shared__ float As[TK][TM + 1];
  __shared__ float Bs[TK][TN];
  float acc[4][4] = {};
  const float* Xb = X + (long long)b * sxB;
  const float* Ab = Xadd ? Xadd + (long long)b * saB : nullptr;
  for (int k0 = 0; k0 < K; k0 += TK) {
#pragma unroll
    for (int v = 0; v < 4; v++) {
      int l = t * 4 + v;
      int i = l >> 4, k = l & 15;
      As[k][i] = W[(long long)(m0 + i) * K + k0 + k];
    }
#pragma unroll
    for (int v = 0; v < 4; v++) {
      int l = t * 4 + v;
      int k = l >> 6, j = l & 63;
      float x = Xb[(long long)(k0 + k) * N + n0 + j];
      if (Ab) x += Ab[(long long)(k0 + k) * N + n0 + j];
      Bs[k][j] = x;
    }
    __syncthreads();
#pragma unroll
    for (int k = 0; k < TK; k++) {
      float a[4], bb[4];
#pragma unroll
      for (int ii = 0; ii < 4; ii++) a[ii] = As[k][ty * 4 + ii];
#pragma unroll
      for (int jj = 0; jj < 4; jj++) bb[jj] = Bs[k][tx * 4 + jj];
#pragma unroll
      for (int ii = 0; ii < 4; ii++)
#pragma unroll
        for (int jj = 0; jj < 4; jj++)
          acc[ii][jj] = fmaf(a[ii], bb[jj], acc[ii][jj]);
    }
    __syncthreads();
  }
#pragma unroll
  for (int ii = 0; ii < 4; ii++) {
    int m = m0 + ty * 4 + ii;
    float sh = bias ? bias[m] : 0.f;
    bool dobn = (bng != nullptr);
    float bnsc = 0.f, bnsh = 0.f;
    if (dobn) {
      bnsc = bng[m] * rsqrtf(bnv[m] + 1e-5f);
      bnsh = bnb[m] - bnm[m] * bnsc;
    }
#pragma unroll
    for (int jj = 0; jj < 4; jj++) {
      int n = n0 + tx * 4 + jj;
      float v = acc[ii][jj] + sh;
      if (dobn) v = fmaxf(v * bnsc + bnsh, 0.f);
      if (Res) v += Res[(long long)b * srB + (long long)m * N + n];
      if (Ybf)
        Ybf[(long long)b * syB + (long long)m * N + n] = f2bf(v);
      else
        Y[(long long)b * syB + (long long)m * N + n] = v;
    }
  }
}

// E[b,r,c] = sum_d q[b,d,r]*q[b,d,c], q: [B, CQ, N].  (bitwise symmetric: same FMA
// order over d for E[r][c] and E[c][r])
__global__ void energy_kernel(const float* __restrict__ q, float* __restrict__ E) {
  const int N = N_DIM;
  int b = blockIdx.z;
  int r0 = blockIdx.y * TM;
  int c0 = blockIdx.x * TN;
  int t = threadIdx.x;
  int tx = t & 15, ty = t >> 4;
  __shared__ float As[TK][TM];
  __shared__ float Bs[TK][TN];
  float acc[4][4] = {};
  const float* qb = q + (long long)b * CQ * N;
  for (int k0 = 0; k0 < CQ; k0 += TK) {
#pragma unroll
    for (int v = 0; v < 4; v++) {
      int l = t * 4 + v;
      int k = l >> 6, j = l & 63;
      As[k][j] = qb[(long long)(k0 + k) * N + r0 + j];
      Bs[k][j] = qb[(long long)(k0 + k) * N + c0 + j];
    }
    __syncthreads();
#pragma unroll
    for (int k = 0; k < TK; k++) {
      float a[4], bb[4];
#pragma unroll
      for (int ii = 0; ii < 4; ii++) a[ii] = As[k][ty * 4 + ii];
#pragma unroll
      for (int jj = 0; jj < 4; jj++) bb[jj] = Bs[k][tx * 4 + jj];
#pragma unroll
      for (int ii = 0; ii < 4; ii++)
#pragma unroll
        for (int jj = 0; jj < 4; jj++)
          acc[ii][jj] = fmaf(a[ii], bb[jj], acc[ii][jj]);
    }
    __syncthreads();
  }
  long long base = (long long)b * N * N;
#pragma unroll
  for (int ii = 0; ii < 4; ii++)
#pragma unroll
    for (int jj = 0; jj < 4; jj++)
      E[base + (long long)(r0 + ty * 4 + ii) * N + c0 + tx * 4 + jj] = acc[ii][jj];
}

// per-row (softmax-row) max and reciprocal exp-sum; one block per row
__global__ void rowstats_kernel(const float* __restrict__ E, float* __restrict__ rmax,
                                float* __restrict__ rinv) {
  const int N = N_DIM;
  long long row = blockIdx.x;
  const float* p = E + row * N;
  int t = threadIdx.x;
  float v[8];
#pragma unroll
  for (int i = 0; i < 8; i++) v[i] = p[t + i * 256];
  float m = v[0];
#pragma unroll
  for (int i = 1; i < 8; i++) m = fmaxf(m, v[i]);
  for (int o = 32; o > 0; o >>= 1) m = fmaxf(m, __shfl_down(m, o, 64));
  __shared__ float red[4];
  int wid = t >> 6, lane = t & 63;
  if (lane == 0) red[wid] = m;
  __syncthreads();
  m = fmaxf(fmaxf(red[0], red[1]), fmaxf(red[2], red[3]));
  __syncthreads();
  float s = 0.f;
#pragma unroll
  for (int i = 0; i < 8; i++) s += __expf(v[i] - m);
  for (int o = 32; o > 0; o >>= 1) s += __shfl_down(s, o, 64);
  if (lane == 0) red[wid] = s;
  __syncthreads();
  if (t == 0) {
    float st = red[0] + red[1] + red[2] + red[3];
    rmax[row] = m;
    rinv[row] = 1.0f / st;
  }
}

// D[b,c,n] = Hprev[b,c,n] - (sum_k val[c,k]*att[k,n]) / (1e-9 + colsum[n])
// att[k,n] generated on the fly from E row n (E symmetric) + rowstats; bf16 MFMA.
// Block: full C (256 rows) x 64 output cols, K tiled by 64. 4 waves, wave w owns
// c rows [w*64, w*64+64). A-tile reg-staged (global short8 -> swizzled ds_write).
__global__ __launch_bounds__(256, 1) void pv_mfma(
    const unsigned short* __restrict__ valbf,  // [B][C][N] bf16
    const float* __restrict__ E,               // [B][N][N]
    const float* __restrict__ rmax, const float* __restrict__ rinv,  // [B][N]
    const float* __restrict__ Hprev, long long shB, float* __restrict__ D) {
  const int N = N_DIM;
  int b = blockIdx.z;
  int n0 = blockIdx.x * PV_BN;
  int t = threadIdx.x;
  int w = t >> 6, l = t & 63;
  int lr = l & 15, lk = l >> 4;
  int brow = t >> 2, bkq = t & 3;  // B-build: thread -> (n-row, k-quad)
  int ar = t >> 3, as_ = t & 7;    // A-stage: thread -> (c-row base, k-slot)

  __shared__ __align__(16) char As[C_DIM * PV_BK * 2];  // 32768 B, row stride 128 B
  __shared__ __align__(16) char Bs[PV_BN * PV_BK * 2];  // 8192 B, row stride 128 B
  __shared__ float csred[4][PV_BN];
  __shared__ float csfin[PV_BN];

  const unsigned short* vb = valbf + (long long)b * C_DIM * N;
  const float* Ebr = E + ((long long)b * N + n0 + brow) * N;  // this thread's E row
  const float* rm = rmax + (long long)b * N;
  const float* ri = rinv + (long long)b * N;

  f32x4 acc[4][4];
#pragma unroll
  for (int i = 0; i < 4; i++)
#pragma unroll
    for (int j = 0; j < 4; j++) acc[i][j] = f32x4{0.f, 0.f, 0.f, 0.f};
  float cs = 0.f;

  // prologue: E/stat registers for tile 0
  float4 ev[4], rv[4], iv[4];
#pragma unroll
  for (int it = 0; it < 4; it++) {
    int kl = bkq * 4 + it * 16;
    ev[it] = *(const float4*)(Ebr + kl);
    rv[it] = *(const float4*)(rm + kl);
    iv[it] = *(const float4*)(ri + kl);
  }

  for (int k0 = 0; k0 < N; k0 += PV_BK) {
    // ---- stage A (val bf16): coalesced short8 loads -> swizzled ds_write ----
    // slot (r, s): 16B at As[r*128 + ((s ^ (r&7))<<4)] <- vb[r*N + k0 + s*8 .. +8)
    short8 areg[8];
#pragma unroll
    for (int it = 0; it < 8; it++) {
      int r = it * 32 + ar;  // 256 threads cover 32 rows x 8 slots per it
      areg[it] = *(const short8*)(vb + (long long)r * N + k0 + as_ * 8);
    }
    // ---- build B tile (att^T, bf16, XOR-swizzled) from registers ----
#pragma unroll
    for (int it = 0; it < 4; it++) {
      int kl = bkq * 4 + it * 16;
      float a0 = __expf(ev[it].x - rv[it].x) * iv[it].x;
      float a1 = __expf(ev[it].y - rv[it].y) * iv[it].y;
      float a2 = __expf(ev[it].z - rv[it].z) * iv[it].z;
      float a3 = __expf(ev[it].w - rv[it].w) * iv[it].w;
      unsigned short u0 = f2bf(a0), u1 = f2bf(a1), u2 = f2bf(a2), u3 = f2bf(a3);
      cs += bf2f(u0) + bf2f(u1) + bf2f(u2) + bf2f(u3);
      uint2 pk;
      pk.x = (unsigned int)u0 | ((unsigned int)u1 << 16);
      pk.y = (unsigned int)u2 | ((unsigned int)u3 << 16);
      *(uint2*)(Bs + brow * 128 + ((((kl >> 3) ^ (brow & 7)) << 4) | ((kl & 7) * 2))) = pk;
    }
    // A ds_writes (after B-build so the global loads have time in flight)
#pragma unroll
    for (int it = 0; it < 8; it++) {
      int r = it * 32 + ar;
      *(short8*)(As + r * 128 + ((as_ ^ (r & 7)) << 4)) = areg[it];
    }
    __syncthreads();
    // ---- prefetch next tile's E/stat regs (in flight under the MFMA phase) ----
    if (k0 + PV_BK < N) {
      int kb = k0 + PV_BK;
#pragma unroll
      for (int it = 0; it < 4; it++) {
        int kl = bkq * 4 + it * 16;
        ev[it] = *(const float4*)(Ebr + kb + kl);
        rv[it] = *(const float4*)(rm + kb + kl);
        iv[it] = *(const float4*)(ri + kb + kl);
      }
    }
    // ---- MFMA compute: 2 sub-steps of K=32 ----
#pragma unroll
    for (int sub = 0; sub < 2; sub++) {
      short8 af[4], bq[4];
#pragma unroll
      for (int ni = 0; ni < 4; ni++) {
        int r = ni * 16 + lr;
        bq[ni] = *(const short8*)(Bs + r * 128 + (((sub * 4 + lk) ^ (r & 7)) << 4));
      }
#pragma unroll
      for (int mi = 0; mi < 4; mi++) {
        int r = w * 64 + mi * 16 + lr;
        af[mi] = *(const short8*)(As + r * 128 + (((sub * 4 + lk) ^ (r & 7)) << 4));
      }
#pragma unroll
      for (int mi = 0; mi < 4; mi++)
#pragma unroll
        for (int ni = 0; ni < 4; ni++)
          acc[mi][ni] =
              __builtin_amdgcn_mfma_f32_16x16x32_bf16(af[mi], bq[ni], acc[mi][ni], 0, 0, 0);
    }
    __syncthreads();
  }

  // ---- column-sum (double-norm denominator) reduce ----
  csred[bkq][brow] = cs;
  __syncthreads();
  if (t < PV_BN) csfin[t] = csred[0][t] + csred[1][t] + csred[2][t] + csred[3][t];
  __syncthreads();

  const float* Hb = Hprev + (long long)b * shB;
  float* Db = D + (long long)b * C_DIM * N;
#pragma unroll
  for (int mi = 0; mi < 4; mi++) {
#pragma unroll
    for (int ni = 0; ni < 4; ni++) {
#pragma unroll
      for (int j = 0; j < 4; j++) {
        int cr = w * 64 + mi * 16 + lk * 4 + j;  // D row = (lane>>4)*4 + reg
        int ml = ni * 16 + lr;                   // D col = lane&15
        float denom = 1e-9f + csfin[ml];
        float xr = acc[mi][ni][j] / denom;
        Db[(long long)cr * N + n0 + ml] = Hb[(long long)cr * N + n0 + ml] - xr;
      }
    }
  }
}

extern "C" void kernel_launch(void* const* d_in, const int* in_sizes, int n_in,
                              void* d_out, int out_size, void* d_ws, size_t ws_size,
                              hipStream_t stream) {
  const float* x = (const float*)d_in[0];
  const float* xyz = (const float*)d_in[1];
  const float* conv1_w = (const float*)d_in[2];
  const float* convpos_w = (const float*)d_in[3];
  const float* bn1_g = (const float*)d_in[4];
  const float* bn1_b = (const float*)d_in[5];
  const float* bn1_m = (const float*)d_in[6];
  const float* bn1_v = (const float*)d_in[7];
  const float* Wqk = (const float*)d_in[8];   // [4,64,256]
  const float* Wv = (const float*)d_in[9];    // [4,256,256]
  const float* bv = (const float*)d_in[10];   // [4,256]
  const float* Wt = (const float*)d_in[11];   // [4,256,256]
  const float* bt = (const float*)d_in[12];   // [4,256]
  const float* bng = (const float*)d_in[13];
  const float* bnb = (const float*)d_in[14];
  const float* bnm = (const float*)d_in[15];
  const float* bnv = (const float*)d_in[16];
  float* out = (float*)d_out;

  const long long BCN = (long long)B_DIM * C_DIM * N_DIM;
  const long long CN = (long long)C_DIM * N_DIM;
  const long long BN = (long long)B_DIM * N_DIM;
  float* ws = (float*)d_ws;
  float* pos = ws;                                       // BCN
  float* h0 = pos + BCN;                                 // BCN
  float* qbuf = h0 + BCN;                                // B*CQ*N
  float* dbuf = qbuf + (long long)B_DIM * CQ * N_DIM;    // BCN
  float* rmax = dbuf + BCN;                              // B*N
  float* rinv = rmax + BN;                               // B*N
  unsigned short* valbf = (unsigned short*)(rinv + BN);  // BCN bf16
  float* E = (float*)(valbf + BCN);                      // B*N*N

  dim3 blk(256);

  pos_kernel<<<dim3(N_DIM / 256, C_DIM, B_DIM), blk, 0, stream>>>(convpos_w, xyz, pos);

  // h0 = relu(bn1(conv1_w @ x))
  gemm_wx<<<dim3(N_DIM / TN, C_DIM / TM, B_DIM), blk, 0, stream>>>(
      conv1_w, x, CN, nullptr, 0, nullptr,
      bn1_g, bn1_b, bn1_m, bn1_v, nullptr, 0, h0, nullptr, CN, C_DIM, C_DIM);

  for (int i = 0; i < 4; i++) {
    const float* hp = (i == 0) ? h0 : out + (long long)(i - 1) * CN;
    long long shp = (i == 0) ? CN : 4 * CN;

    // q = Wqk_i @ (h + pos)   (fp32)
    gemm_wx<<<dim3(N_DIM / TN, CQ / TM, B_DIM), blk, 0, stream>>>(
        Wqk + (long long)i * CQ * C_DIM, hp, shp, pos, CN, nullptr,
        nullptr, nullptr, nullptr, nullptr, nullptr, 0,
        qbuf, nullptr, (long long)CQ * N_DIM, CQ, C_DIM);

    // val = Wv_i @ (h + pos) + bv_i   (bf16 output for MFMA PV)
    gemm_wx<<<dim3(N_DIM / TN, C_DIM / TM, B_DIM), blk, 0, stream>>>(
        Wv + (long long)i * C_DIM * C_DIM, hp, shp, pos, CN, bv + i * C_DIM,
        nullptr, nullptr, nullptr, nullptr, nullptr, 0,
        nullptr, valbf, CN, C_DIM, C_DIM);

    // E = q^T q   (fp32, bitwise symmetric)
    energy_kernel<<<dim3(N_DIM / TN, N_DIM / TM, B_DIM), blk, 0, stream>>>(qbuf, E);

    // per-row softmax stats
    rowstats_kernel<<<dim3(B_DIM * N_DIM), blk, 0, stream>>>(E, rmax, rinv);

    // D = h - (val @ att)/colsum, att built on the fly (bf16 MFMA)
    pv_mfma<<<dim3(N_DIM / PV_BN, 1, B_DIM), blk, 0, stream>>>(
        valbf, E, rmax, rinv, hp, shp, dbuf);

    // out_i = h + relu(bn_i(Wt_i @ d + bt_i))
    gemm_wx<<<dim3(N_DIM / TN, C_DIM / TM, B_DIM), blk, 0, stream>>>(
        Wt + (long long)i * C_DIM * C_DIM, dbuf, CN, nullptr, 0, bt + i * C_DIM,
        bng + i * C_DIM, bnb + i * C_DIM, bnm + i * C_DIM, bnv + i * C_DIM,
        hp, shp, out + (long long)i * CN, nullptr, 4 * CN, C_DIM, C_DIM);
  }
}

// Round 4
// 871.982 us; speedup vs baseline: 3.0342x; 1.3117x over previous
//
#include <hip/hip_runtime.h>
#include <hip/hip_bf16.h>
#include <math.h>

#define B_DIM 8
#define C_DIM 256
#define N_DIM 2048
#define CQ 64

#define TM 64
#define TN 64
#define TK 16

#define PV_BN 64
#define PV_BK 64

using short8 = __attribute__((ext_vector_type(8))) short;
using f32x4 = __attribute__((ext_vector_type(4))) float;

__device__ __forceinline__ unsigned short f2bf(float x) {
  union { float f; unsigned int u; } c; c.f = x;
  unsigned int r = c.u + 0x7fffu + ((c.u >> 16) & 1u);
  return (unsigned short)(r >> 16);
}
__device__ __forceinline__ float bf2f(unsigned short u) {
  union { unsigned int ui; float f; } c; c.ui = ((unsigned int)u) << 16;
  return c.f;
}

// split fp32 -> (hi, lo) bf16 pair: v ~= hi + lo
__global__ void split_kernel(const float* __restrict__ src, unsigned short* __restrict__ hi,
                             unsigned short* __restrict__ lo, int count) {
  int i = blockIdx.x * 256 + threadIdx.x;
  if (i < count) {
    float v = src[i];
    unsigned short h = f2bf(v);
    hi[i] = h;
    lo[i] = f2bf(v - bf2f(h));
  }
}

// pos[b,c,n] = sum_i w[c,i]*xyz[b,n,i]
__global__ void pos_kernel(const float* __restrict__ w, const float* __restrict__ xyz,
                           float* __restrict__ pos) {
  int n = blockIdx.x * blockDim.x + threadIdx.x;
  int c = blockIdx.y;
  int b = blockIdx.z;
  const float* xp = xyz + ((long long)b * N_DIM + n) * 3;
  pos[((long long)b * C_DIM + c) * N_DIM + n] =
      w[c * 3 + 0] * xp[0] + w[c * 3 + 1] * xp[1] + w[c * 3 + 2] * xp[2];
}

// fp32 VALU GEMM (kept only for the small q projection, M=64)
__global__ void gemm_wx(const float* __restrict__ W,
                        const float* __restrict__ X, long long sxB,
                        const float* __restrict__ Xadd, long long saB,
                        const float* __restrict__ bias,
                        const float* __restrict__ bng, const float* __restrict__ bnb,
                        const float* __restrict__ bnm, const float* __restrict__ bnv,
                        const float* __restrict__ Res, long long srB,
                        float* __restrict__ Y, unsigned short* __restrict__ Ybf,
                        long long syB, int M, int K) {
  const int N = N_DIM;
  int b = blockIdx.z;
  int m0 = blockIdx.y * TM;
  int n0 = blockIdx.x * TN;
  int t = threadIdx.x;
  int tx = t & 15, ty = t >> 4;
  __shared__ float As[TK][TM + 1];
  __shared__ float Bs[TK][TN];
  float acc[4][4] = {};
  const float* Xb = X + (long long)b * sxB;
  const float* Ab = Xadd ? Xadd + (long long)b * saB : nullptr;
  for (int k0 = 0; k0 < K; k0 += TK) {
#pragma unroll
    for (int v = 0; v < 4; v++) {
      int l = t * 4 + v;
      int i = l >> 4, k = l & 15;
      As[k][i] = W[(long long)(m0 + i) * K + k0 + k];
    }
#pragma unroll
    for (int v = 0; v < 4; v++) {
      int l = t * 4 + v;
      int k = l >> 6, j = l & 63;
      float x = Xb[(long long)(k0 + k) * N + n0 + j];
      if (Ab) x += Ab[(long long)(k0 + k) * N + n0 + j];
      Bs[k][j] = x;
    }
    __syncthreads();
#pragma unroll
    for (int k = 0; k < TK; k++) {
      float a[4], bb[4];
#pragma unroll
      for (int ii = 0; ii < 4; ii++) a[ii] = As[k][ty * 4 + ii];
#pragma unroll
      for (int jj = 0; jj < 4; jj++) bb[jj] = Bs[k][tx * 4 + jj];
#pragma unroll
      for (int ii = 0; ii < 4; ii++)
#pragma unroll
        for (int jj = 0; jj < 4; jj++)
          acc[ii][jj] = fmaf(a[ii], bb[jj], acc[ii][jj]);
    }
    __syncthreads();
  }
#pragma unroll
  for (int ii = 0; ii < 4; ii++) {
    int m = m0 + ty * 4 + ii;
    float sh = bias ? bias[m] : 0.f;
    bool dobn = (bng != nullptr);
    float bnsc = 0.f, bnsh = 0.f;
    if (dobn) {
      bnsc = bng[m] * rsqrtf(bnv[m] + 1e-5f);
      bnsh = bnb[m] - bnm[m] * bnsc;
    }
#pragma unroll
    for (int jj = 0; jj < 4; jj++) {
      int n = n0 + tx * 4 + jj;
      float v = acc[ii][jj] + sh;
      if (dobn) v = fmaxf(v * bnsc + bnsh, 0.f);
      if (Res) v += Res[(long long)b * srB + (long long)m * N + n];
      if (Ybf)
        Ybf[(long long)b * syB + (long long)m * N + n] = f2bf(v);
      else
        Y[(long long)b * syB + (long long)m * N + n] = v;
    }
  }
}

// Y[b,m,n] = epi( sum_k W[m,k]*(X[b,k,n]+Xadd) ) via split-bf16 MFMA (3 products).
// Block: 128 rows (4 waves x 32) x 64 cols; K=256 in 4 steps of 64.
// W pre-split (Whi/Wlo bf16, row-major, k-contiguous); X split on the fly with
// in-LDS transpose (coalesced-over-n global reads).
__global__ __launch_bounds__(256) void gemm_mfma(
    const unsigned short* __restrict__ Whi, const unsigned short* __restrict__ Wlo,
    const float* __restrict__ X, long long sxB,
    const float* __restrict__ Xadd, long long saB,
    const float* __restrict__ bias,
    const float* __restrict__ bng, const float* __restrict__ bnb,
    const float* __restrict__ bnm, const float* __restrict__ bnv,
    const float* __restrict__ Res, long long srB,
    float* __restrict__ Y, unsigned short* __restrict__ Ybf, long long syB) {
  const int N = N_DIM, K = C_DIM;
  int b = blockIdx.z;
  int m0 = blockIdx.y * 128;
  int n0 = blockIdx.x * 64;
  int t = threadIdx.x;
  int w = t >> 6, l = t & 63;
  int lr = l & 15, lk = l >> 4;
  int j = t & 63, dq = t >> 6;   // B staging: col j, k-16-group dq
  int ar = t >> 3, as_ = t & 7;  // A staging: row-slot, k-octet

  __shared__ __align__(16) char Ah[128 * 128];  // [128 m][64 k] bf16, swizzled
  __shared__ __align__(16) char Al[128 * 128];
  __shared__ __align__(16) char Bh[64 * 128];  // [64 n][64 k] bf16, swizzled
  __shared__ __align__(16) char Bl[64 * 128];

  const float* Xb = X + (long long)b * sxB;
  const float* Adb = Xadd ? Xadd + (long long)b * saB : nullptr;

  f32x4 acc[2][4];
#pragma unroll
  for (int i = 0; i < 2; i++)
#pragma unroll
    for (int jq = 0; jq < 4; jq++) acc[i][jq] = f32x4{0.f, 0.f, 0.f, 0.f};

  for (int k0 = 0; k0 < K; k0 += 64) {
    // A: Whi/Wlo rows m0..m0+128, k-slice (coalesced short8)
    short8 wh[4], wl[4];
#pragma unroll
    for (int it = 0; it < 4; it++) {
      int r = it * 32 + ar;
      wh[it] = *(const short8*)(Whi + (long long)(m0 + r) * K + k0 + as_ * 8);
      wl[it] = *(const short8*)(Wlo + (long long)(m0 + r) * K + k0 + as_ * 8);
    }
    // B: X[k0+dq*16..+16][n0+j] (+Xadd), transpose + split
    float v[16];
#pragma unroll
    for (int i = 0; i < 16; i++) {
      float x = Xb[(long long)(k0 + dq * 16 + i) * N + n0 + j];
      if (Adb) x += Adb[(long long)(k0 + dq * 16 + i) * N + n0 + j];
      v[i] = x;
    }
    unsigned int ph[8], pl[8];
#pragma unroll
    for (int i = 0; i < 8; i++) {
      unsigned short h0 = f2bf(v[2 * i]), h1 = f2bf(v[2 * i + 1]);
      unsigned short l0 = f2bf(v[2 * i] - bf2f(h0)), l1 = f2bf(v[2 * i + 1] - bf2f(h1));
      ph[i] = (unsigned int)h0 | ((unsigned int)h1 << 16);
      pl[i] = (unsigned int)l0 | ((unsigned int)l1 << 16);
    }
    // LDS writes
#pragma unroll
    for (int it = 0; it < 4; it++) {
      int r = it * 32 + ar;
      *(short8*)(Ah + r * 128 + ((as_ ^ (r & 7)) << 4)) = wh[it];
      *(short8*)(Al + r * 128 + ((as_ ^ (r & 7)) << 4)) = wl[it];
    }
    {
      int o0 = dq * 2, o1 = dq * 2 + 1;
      *(uint4*)(Bh + j * 128 + ((o0 ^ (j & 7)) << 4)) = make_uint4(ph[0], ph[1], ph[2], ph[3]);
      *(uint4*)(Bh + j * 128 + ((o1 ^ (j & 7)) << 4)) = make_uint4(ph[4], ph[5], ph[6], ph[7]);
      *(uint4*)(Bl + j * 128 + ((o0 ^ (j & 7)) << 4)) = make_uint4(pl[0], pl[1], pl[2], pl[3]);
      *(uint4*)(Bl + j * 128 + ((o1 ^ (j & 7)) << 4)) = make_uint4(pl[4], pl[5], pl[6], pl[7]);
    }
    __syncthreads();
    // compute: 2 sub-K of 32; products hi*hi + hi*lo + lo*hi
#pragma unroll
    for (int sub = 0; sub < 2; sub++) {
      short8 ah[2], al2[2], bh[4], bl[4];
#pragma unroll
      for (int mi = 0; mi < 2; mi++) {
        int ra = w * 32 + mi * 16 + lr;
        ah[mi] = *(const short8*)(Ah + ra * 128 + (((sub * 4 + lk) ^ (ra & 7)) << 4));
        al2[mi] = *(const short8*)(Al + ra * 128 + (((sub * 4 + lk) ^ (ra & 7)) << 4));
      }
#pragma unroll
      for (int ni = 0; ni < 4; ni++) {
        int rb = ni * 16 + lr;
        bh[ni] = *(const short8*)(Bh + rb * 128 + (((sub * 4 + lk) ^ (rb & 7)) << 4));
        bl[ni] = *(const short8*)(Bl + rb * 128 + (((sub * 4 + lk) ^ (rb & 7)) << 4));
      }
#pragma unroll
      for (int mi = 0; mi < 2; mi++)
#pragma unroll
        for (int ni = 0; ni < 4; ni++) {
          acc[mi][ni] = __builtin_amdgcn_mfma_f32_16x16x32_bf16(ah[mi], bh[ni], acc[mi][ni], 0, 0, 0);
          acc[mi][ni] = __builtin_amdgcn_mfma_f32_16x16x32_bf16(ah[mi], bl[ni], acc[mi][ni], 0, 0, 0);
          acc[mi][ni] = __builtin_amdgcn_mfma_f32_16x16x32_bf16(al2[mi], bh[ni], acc[mi][ni], 0, 0, 0);
        }
    }
    __syncthreads();
  }
  // epilogue
#pragma unroll
  for (int mi = 0; mi < 2; mi++) {
#pragma unroll
    for (int jj = 0; jj < 4; jj++) {
      int m = m0 + w * 32 + mi * 16 + lk * 4 + jj;
      float sh = bias ? bias[m] : 0.f;
      bool dobn = (bng != nullptr);
      float bnsc = 0.f, bnsh = 0.f;
      if (dobn) {
        bnsc = bng[m] * rsqrtf(bnv[m] + 1e-5f);
        bnsh = bnb[m] - bnm[m] * bnsc;
      }
#pragma unroll
      for (int ni = 0; ni < 4; ni++) {
        int n = n0 + ni * 16 + lr;
        float vv = acc[mi][ni][jj] + sh;
        if (dobn) vv = fmaxf(vv * bnsc + bnsh, 0.f);
        if (Res) vv += Res[(long long)b * srB + (long long)m * N + n];
        if (Ybf)
          Ybf[(long long)b * syB + (long long)m * N + n] = f2bf(vv);
        else
          Y[(long long)b * syB + (long long)m * N + n] = vv;
      }
    }
  }
}

// E[b,r,c] = sum_d q[b,d,r]*q[b,d,c] via split-bf16 MFMA. 64x64 tile, K=CQ=64.
// q read fp32, transpose+split into LDS during staging.
__global__ __launch_bounds__(256) void energy_mfma(const float* __restrict__ q,
                                                   float* __restrict__ E) {
  const int N = N_DIM;
  int b = blockIdx.z;
  int r0 = blockIdx.y * 64;
  int c0 = blockIdx.x * 64;
  int t = threadIdx.x;
  int w = t >> 6, l = t & 63;
  int lr = l & 15, lk = l >> 4;
  int j = t & 63, dq = t >> 6;

  __shared__ __align__(16) char Ah[64 * 128];
  __shared__ __align__(16) char Al[64 * 128];
  __shared__ __align__(16) char Bh[64 * 128];
  __shared__ __align__(16) char Bl[64 * 128];

  const float* qb = q + (long long)b * CQ * N;
  {
    float va[16], vb[16];
#pragma unroll
    for (int i = 0; i < 16; i++) {
      va[i] = qb[(long long)(dq * 16 + i) * N + r0 + j];
      vb[i] = qb[(long long)(dq * 16 + i) * N + c0 + j];
    }
    unsigned int pah[8], pal[8], pbh[8], pbl[8];
#pragma unroll
    for (int i = 0; i < 8; i++) {
      unsigned short h0 = f2bf(va[2 * i]), h1 = f2bf(va[2 * i + 1]);
      unsigned short l0 = f2bf(va[2 * i] - bf2f(h0)), l1 = f2bf(va[2 * i + 1] - bf2f(h1));
      pah[i] = (unsigned int)h0 | ((unsigned int)h1 << 16);
      pal[i] = (unsigned int)l0 | ((unsigned int)l1 << 16);
      unsigned short g0 = f2bf(vb[2 * i]), g1 = f2bf(vb[2 * i + 1]);
      unsigned short m0_ = f2bf(vb[2 * i] - bf2f(g0)), m1 = f2bf(vb[2 * i + 1] - bf2f(g1));
      pbh[i] = (unsigned int)g0 | ((unsigned int)g1 << 16);
      pbl[i] = (unsigned int)m0_ | ((unsigned int)m1 << 16);
    }
    int o0 = dq * 2, o1 = dq * 2 + 1;
    *(uint4*)(Ah + j * 128 + ((o0 ^ (j & 7)) << 4)) = make_uint4(pah[0], pah[1], pah[2], pah[3]);
    *(uint4*)(Ah + j * 128 + ((o1 ^ (j & 7)) << 4)) = make_uint4(pah[4], pah[5], pah[6], pah[7]);
    *(uint4*)(Al + j * 128 + ((o0 ^ (j & 7)) << 4)) = make_uint4(pal[0], pal[1], pal[2], pal[3]);
    *(uint4*)(Al + j * 128 + ((o1 ^ (j & 7)) << 4)) = make_uint4(pal[4], pal[5], pal[6], pal[7]);
    *(uint4*)(Bh + j * 128 + ((o0 ^ (j & 7)) << 4)) = make_uint4(pbh[0], pbh[1], pbh[2], pbh[3]);
    *(uint4*)(Bh + j * 128 + ((o1 ^ (j & 7)) << 4)) = make_uint4(pbh[4], pbh[5], pbh[6], pbh[7]);
    *(uint4*)(Bl + j * 128 + ((o0 ^ (j & 7)) << 4)) = make_uint4(pbl[0], pbl[1], pbl[2], pbl[3]);
    *(uint4*)(Bl + j * 128 + ((o1 ^ (j & 7)) << 4)) = make_uint4(pbl[4], pbl[5], pbl[6], pbl[7]);
  }
  __syncthreads();

  f32x4 acc[4];
#pragma unroll
  for (int i = 0; i < 4; i++) acc[i] = f32x4{0.f, 0.f, 0.f, 0.f};
#pragma unroll
  for (int sub = 0; sub < 2; sub++) {
    int ra = w * 16 + lr;
    short8 ah = *(const short8*)(Ah + ra * 128 + (((sub * 4 + lk) ^ (ra & 7)) << 4));
    short8 al = *(const short8*)(Al + ra * 128 + (((sub * 4 + lk) ^ (ra & 7)) << 4));
    short8 bh[4], bl[4];
#pragma unroll
    for (int ni = 0; ni < 4; ni++) {
      int rb = ni * 16 + lr;
      bh[ni] = *(const short8*)(Bh + rb * 128 + (((sub * 4 + lk) ^ (rb & 7)) << 4));
      bl[ni] = *(const short8*)(Bl + rb * 128 + (((sub * 4 + lk) ^ (rb & 7)) << 4));
    }
#pragma unroll
    for (int ni = 0; ni < 4; ni++) {
      acc[ni] = __builtin_amdgcn_mfma_f32_16x16x32_bf16(ah, bh[ni], acc[ni], 0, 0, 0);
      acc[ni] = __builtin_amdgcn_mfma_f32_16x16x32_bf16(ah, bl[ni], acc[ni], 0, 0, 0);
      acc[ni] = __builtin_amdgcn_mfma_f32_16x16x32_bf16(al, bh[ni], acc[ni], 0, 0, 0);
    }
  }
  long long base = (long long)b * N * N;
#pragma unroll
  for (int ni = 0; ni < 4; ni++)
#pragma unroll
    for (int jj = 0; jj < 4; jj++)
      E[base + (long long)(r0 + w * 16 + lk * 4 + jj) * N + c0 + ni * 16 + lr] = acc[ni][jj];
}

// per-row (softmax-row) max and reciprocal exp-sum; one block per row
__global__ void rowstats_kernel(const float* __restrict__ E, float* __restrict__ rmax,
                                float* __restrict__ rinv) {
  const int N = N_DIM;
  long long row = blockIdx.x;
  const float* p = E + row * N;
  int t = threadIdx.x;
  float v[8];
#pragma unroll
  for (int i = 0; i < 8; i++) v[i] = p[t + i * 256];
  float m = v[0];
#pragma unroll
  for (int i = 1; i < 8; i++) m = fmaxf(m, v[i]);
  for (int o = 32; o > 0; o >>= 1) m = fmaxf(m, __shfl_down(m, o, 64));
  __shared__ float red[4];
  int wid = t >> 6, lane = t & 63;
  if (lane == 0) red[wid] = m;
  __syncthreads();
  m = fmaxf(fmaxf(red[0], red[1]), fmaxf(red[2], red[3]));
  __syncthreads();
  float s = 0.f;
#pragma unroll
  for (int i = 0; i < 8; i++) s += __expf(v[i] - m);
  for (int o = 32; o > 0; o >>= 1) s += __shfl_down(s, o, 64);
  if (lane == 0) red[wid] = s;
  __syncthreads();
  if (t == 0) {
    float st = red[0] + red[1] + red[2] + red[3];
    rmax[row] = m;
    rinv[row] = 1.0f / st;
  }
}

// D[b,c,n] = Hprev - (val @ att)/colsum; att built on the fly from E rows (symmetry).
__global__ __launch_bounds__(256, 1) void pv_mfma(
    const unsigned short* __restrict__ valbf,
    const float* __restrict__ E,
    const float* __restrict__ rmax, const float* __restrict__ rinv,
    const float* __restrict__ Hprev, long long shB, float* __restrict__ D) {
  const int N = N_DIM;
  int b = blockIdx.z;
  int n0 = blockIdx.x * PV_BN;
  int t = threadIdx.x;
  int w = t >> 6, l = t & 63;
  int lr = l & 15, lk = l >> 4;
  int brow = t >> 2, bkq = t & 3;
  int ar = t >> 3, as_ = t & 7;

  __shared__ __align__(16) char As[C_DIM * PV_BK * 2];
  __shared__ __align__(16) char Bs[PV_BN * PV_BK * 2];
  __shared__ float csred[4][PV_BN];
  __shared__ float csfin[PV_BN];

  const unsigned short* vb = valbf + (long long)b * C_DIM * N;
  const float* Ebr = E + ((long long)b * N + n0 + brow) * N;
  const float* rm = rmax + (long long)b * N;
  const float* ri = rinv + (long long)b * N;

  f32x4 acc[4][4];
#pragma unroll
  for (int i = 0; i < 4; i++)
#pragma unroll
    for (int jq = 0; jq < 4; jq++) acc[i][jq] = f32x4{0.f, 0.f, 0.f, 0.f};
  float cs = 0.f;

  float4 ev[4], rv[4], iv[4];
#pragma unroll
  for (int it = 0; it < 4; it++) {
    int kl = bkq * 4 + it * 16;
    ev[it] = *(const float4*)(Ebr + kl);
    rv[it] = *(const float4*)(rm + kl);
    iv[it] = *(const float4*)(ri + kl);
  }

  for (int k0 = 0; k0 < N; k0 += PV_BK) {
    short8 areg[8];
#pragma unroll
    for (int it = 0; it < 8; it++) {
      int r = it * 32 + ar;
      areg[it] = *(const short8*)(vb + (long long)r * N + k0 + as_ * 8);
    }
#pragma unroll
    for (int it = 0; it < 4; it++) {
      int kl = bkq * 4 + it * 16;
      float a0 = __expf(ev[it].x - rv[it].x) * iv[it].x;
      float a1 = __expf(ev[it].y - rv[it].y) * iv[it].y;
      float a2 = __expf(ev[it].z - rv[it].z) * iv[it].z;
      float a3 = __expf(ev[it].w - rv[it].w) * iv[it].w;
      unsigned short u0 = f2bf(a0), u1 = f2bf(a1), u2 = f2bf(a2), u3 = f2bf(a3);
      cs += bf2f(u0) + bf2f(u1) + bf2f(u2) + bf2f(u3);
      uint2 pk;
      pk.x = (unsigned int)u0 | ((unsigned int)u1 << 16);
      pk.y = (unsigned int)u2 | ((unsigned int)u3 << 16);
      *(uint2*)(Bs + brow * 128 + ((((kl >> 3) ^ (brow & 7)) << 4) | ((kl & 7) * 2))) = pk;
    }
#pragma unroll
    for (int it = 0; it < 8; it++) {
      int r = it * 32 + ar;
      *(short8*)(As + r * 128 + ((as_ ^ (r & 7)) << 4)) = areg[it];
    }
    __syncthreads();
    if (k0 + PV_BK < N) {
      int kb = k0 + PV_BK;
#pragma unroll
      for (int it = 0; it < 4; it++) {
        int kl = bkq * 4 + it * 16;
        ev[it] = *(const float4*)(Ebr + kb + kl);
        rv[it] = *(const float4*)(rm + kb + kl);
        iv[it] = *(const float4*)(ri + kb + kl);
      }
    }
#pragma unroll
    for (int sub = 0; sub < 2; sub++) {
      short8 af[4], bq[4];
#pragma unroll
      for (int ni = 0; ni < 4; ni++) {
        int r = ni * 16 + lr;
        bq[ni] = *(const short8*)(Bs + r * 128 + (((sub * 4 + lk) ^ (r & 7)) << 4));
      }
#pragma unroll
      for (int mi = 0; mi < 4; mi++) {
        int r = w * 64 + mi * 16 + lr;
        af[mi] = *(const short8*)(As + r * 128 + (((sub * 4 + lk) ^ (r & 7)) << 4));
      }
#pragma unroll
      for (int mi = 0; mi < 4; mi++)
#pragma unroll
        for (int ni = 0; ni < 4; ni++)
          acc[mi][ni] =
              __builtin_amdgcn_mfma_f32_16x16x32_bf16(af[mi], bq[ni], acc[mi][ni], 0, 0, 0);
    }
    __syncthreads();
  }

  csred[bkq][brow] = cs;
  __syncthreads();
  if (t < PV_BN) csfin[t] = csred[0][t] + csred[1][t] + csred[2][t] + csred[3][t];
  __syncthreads();

  const float* Hb = Hprev + (long long)b * shB;
  float* Db = D + (long long)b * C_DIM * N;
#pragma unroll
  for (int mi = 0; mi < 4; mi++) {
#pragma unroll
    for (int ni = 0; ni < 4; ni++) {
#pragma unroll
      for (int jj = 0; jj < 4; jj++) {
        int cr = w * 64 + mi * 16 + lk * 4 + jj;
        int ml = ni * 16 + lr;
        float denom = 1e-9f + csfin[ml];
        float xr = acc[mi][ni][jj] / denom;
        Db[(long long)cr * N + n0 + ml] = Hb[(long long)cr * N + n0 + ml] - xr;
      }
    }
  }
}

extern "C" void kernel_launch(void* const* d_in, const int* in_sizes, int n_in,
                              void* d_out, int out_size, void* d_ws, size_t ws_size,
                              hipStream_t stream) {
  const float* x = (const float*)d_in[0];
  const float* xyz = (const float*)d_in[1];
  const float* conv1_w = (const float*)d_in[2];
  const float* convpos_w = (const float*)d_in[3];
  const float* bn1_g = (const float*)d_in[4];
  const float* bn1_b = (const float*)d_in[5];
  const float* bn1_m = (const float*)d_in[6];
  const float* bn1_v = (const float*)d_in[7];
  const float* Wqk = (const float*)d_in[8];   // [4,64,256]
  const float* Wv = (const float*)d_in[9];    // [4,256,256]
  const float* bv = (const float*)d_in[10];   // [4,256]
  const float* Wt = (const float*)d_in[11];   // [4,256,256]
  const float* bt = (const float*)d_in[12];   // [4,256]
  const float* bng = (const float*)d_in[13];
  const float* bnb = (const float*)d_in[14];
  const float* bnm = (const float*)d_in[15];
  const float* bnv = (const float*)d_in[16];
  float* out = (float*)d_out;

  const long long BCN = (long long)B_DIM * C_DIM * N_DIM;
  const long long CN = (long long)C_DIM * N_DIM;
  const long long BN = (long long)B_DIM * N_DIM;
  const int WSZ = C_DIM * C_DIM;  // 65536
  float* ws = (float*)d_ws;
  float* pos = ws;                                       // BCN
  float* h0 = pos + BCN;                                 // BCN
  float* qbuf = h0 + BCN;                                // B*CQ*N
  float* dbuf = qbuf + (long long)B_DIM * CQ * N_DIM;    // BCN
  float* rmax = dbuf + BCN;                              // B*N
  float* rinv = rmax + BN;                               // B*N
  unsigned short* valbf = (unsigned short*)(rinv + BN);  // BCN bf16
  unsigned short* whi = valbf + BCN;                     // 9*65536 bf16
  unsigned short* wlo = whi + 9 * WSZ;                   // 9*65536 bf16
  float* E = (float*)(wlo + 9 * WSZ);                    // B*N*N

  // whi/wlo layout: [0]=conv1, [1..4]=Wv_i, [5..8]=Wt_i
  unsigned short* c1hi = whi;
  unsigned short* c1lo = wlo;
  unsigned short* wvhi = whi + WSZ;
  unsigned short* wvlo = wlo + WSZ;
  unsigned short* wthi = whi + 5 * WSZ;
  unsigned short* wtlo = wlo + 5 * WSZ;

  dim3 blk(256);

  split_kernel<<<dim3(WSZ / 256), blk, 0, stream>>>(conv1_w, c1hi, c1lo, WSZ);
  split_kernel<<<dim3(4 * WSZ / 256), blk, 0, stream>>>(Wv, wvhi, wvlo, 4 * WSZ);
  split_kernel<<<dim3(4 * WSZ / 256), blk, 0, stream>>>(Wt, wthi, wtlo, 4 * WSZ);

  pos_kernel<<<dim3(N_DIM / 256, C_DIM, B_DIM), blk, 0, stream>>>(convpos_w, xyz, pos);

  // h0 = relu(bn1(conv1_w @ x))
  gemm_mfma<<<dim3(N_DIM / 64, 2, B_DIM), blk, 0, stream>>>(
      c1hi, c1lo, x, CN, nullptr, 0, nullptr,
      bn1_g, bn1_b, bn1_m, bn1_v, nullptr, 0, h0, nullptr, CN);

  for (int i = 0; i < 4; i++) {
    const float* hp = (i == 0) ? h0 : out + (long long)(i - 1) * CN;
    long long shp = (i == 0) ? CN : 4 * CN;

    // q = Wqk_i @ (h + pos)   (fp32 VALU, exact)
    gemm_wx<<<dim3(N_DIM / TN, CQ / TM, B_DIM), blk, 0, stream>>>(
        Wqk + (long long)i * CQ * C_DIM, hp, shp, pos, CN, nullptr,
        nullptr, nullptr, nullptr, nullptr, nullptr, 0,
        qbuf, nullptr, (long long)CQ * N_DIM, CQ, C_DIM);

    // val = Wv_i @ (h + pos) + bv_i  (split-bf16 MFMA, bf16 out)
    gemm_mfma<<<dim3(N_DIM / 64, 2, B_DIM), blk, 0, stream>>>(
        wvhi + (long long)i * WSZ, wvlo + (long long)i * WSZ, hp, shp, pos, CN,
        bv + i * C_DIM, nullptr, nullptr, nullptr, nullptr, nullptr, 0,
        nullptr, valbf, CN);

    // E = q^T q   (split-bf16 MFMA, fp32 out)
    energy_mfma<<<dim3(N_DIM / 64, N_DIM / 64, B_DIM), blk, 0, stream>>>(qbuf, E);

    rowstats_kernel<<<dim3(B_DIM * N_DIM), blk, 0, stream>>>(E, rmax, rinv);

    pv_mfma<<<dim3(N_DIM / PV_BN, 1, B_DIM), blk, 0, stream>>>(
        valbf, E, rmax, rinv, hp, shp, dbuf);

    // out_i = h + relu(bn_i(Wt_i @ d + bt_i))  (split-bf16 MFMA)
    gemm_mfma<<<dim3(N_DIM / 64, 2, B_DIM), blk, 0, stream>>>(
        wthi + (long long)i * WSZ, wtlo + (long long)i * WSZ, dbuf, CN, nullptr, 0,
        bt + i * C_DIM, bng + i * C_DIM, bnb + i * C_DIM, bnm + i * C_DIM, bnv + i * C_DIM,
        hp, shp, out + (long long)i * CN, nullptr, 4 * CN);
  }
}

// Round 5
// 826.800 us; speedup vs baseline: 3.2000x; 1.0546x over previous
//
#include <hip/hip_runtime.h>
#include <hip/hip_bf16.h>
#include <math.h>

#define B_DIM 8
#define C_DIM 256
#define N_DIM 2048
#define CQ 64

#define TM 64
#define TN 64
#define TK 16

#define PV_BN 32
#define PV_BK 64

using short8 = __attribute__((ext_vector_type(8))) short;
using f32x4 = __attribute__((ext_vector_type(4))) float;

__device__ __forceinline__ unsigned short f2bf(float x) {
  union { float f; unsigned int u; } c; c.f = x;
  unsigned int r = c.u + 0x7fffu + ((c.u >> 16) & 1u);
  return (unsigned short)(r >> 16);
}
__device__ __forceinline__ float bf2f(unsigned short u) {
  union { unsigned int ui; float f; } c; c.ui = ((unsigned int)u) << 16;
  return c.f;
}

// split fp32 -> (hi, lo) bf16 pair: v ~= hi + lo
__global__ void split_kernel(const float* __restrict__ src, unsigned short* __restrict__ hi,
                             unsigned short* __restrict__ lo, int count) {
  int i = blockIdx.x * 256 + threadIdx.x;
  if (i < count) {
    float v = src[i];
    unsigned short h = f2bf(v);
    hi[i] = h;
    lo[i] = f2bf(v - bf2f(h));
  }
}

// pos[b,c,n] = sum_i w[c,i]*xyz[b,n,i]
__global__ void pos_kernel(const float* __restrict__ w, const float* __restrict__ xyz,
                           float* __restrict__ pos) {
  int n = blockIdx.x * blockDim.x + threadIdx.x;
  int c = blockIdx.y;
  int b = blockIdx.z;
  const float* xp = xyz + ((long long)b * N_DIM + n) * 3;
  pos[((long long)b * C_DIM + c) * N_DIM + n] =
      w[c * 3 + 0] * xp[0] + w[c * 3 + 1] * xp[1] + w[c * 3 + 2] * xp[2];
}

// fp32 VALU GEMM (kept only for the small q projection, M=64)
__global__ void gemm_wx(const float* __restrict__ W,
                        const float* __restrict__ X, long long sxB,
                        const float* __restrict__ Xadd, long long saB,
                        const float* __restrict__ bias,
                        const float* __restrict__ bng, const float* __restrict__ bnb,
                        const float* __restrict__ bnm, const float* __restrict__ bnv,
                        const float* __restrict__ Res, long long srB,
                        float* __restrict__ Y, unsigned short* __restrict__ Ybf,
                        long long syB, int M, int K) {
  const int N = N_DIM;
  int b = blockIdx.z;
  int m0 = blockIdx.y * TM;
  int n0 = blockIdx.x * TN;
  int t = threadIdx.x;
  int tx = t & 15, ty = t >> 4;
  __shared__ float As[TK][TM + 1];
  __shared__ float Bs[TK][TN];
  float acc[4][4] = {};
  const float* Xb = X + (long long)b * sxB;
  const float* Ab = Xadd ? Xadd + (long long)b * saB : nullptr;
  for (int k0 = 0; k0 < K; k0 += TK) {
#pragma unroll
    for (int v = 0; v < 4; v++) {
      int l = t * 4 + v;
      int i = l >> 4, k = l & 15;
      As[k][i] = W[(long long)(m0 + i) * K + k0 + k];
    }
#pragma unroll
    for (int v = 0; v < 4; v++) {
      int l = t * 4 + v;
      int k = l >> 6, j = l & 63;
      float x = Xb[(long long)(k0 + k) * N + n0 + j];
      if (Ab) x += Ab[(long long)(k0 + k) * N + n0 + j];
      Bs[k][j] = x;
    }
    __syncthreads();
#pragma unroll
    for (int k = 0; k < TK; k++) {
      float a[4], bb[4];
#pragma unroll
      for (int ii = 0; ii < 4; ii++) a[ii] = As[k][ty * 4 + ii];
#pragma unroll
      for (int jj = 0; jj < 4; jj++) bb[jj] = Bs[k][tx * 4 + jj];
#pragma unroll
      for (int ii = 0; ii < 4; ii++)
#pragma unroll
        for (int jj = 0; jj < 4; jj++)
          acc[ii][jj] = fmaf(a[ii], bb[jj], acc[ii][jj]);
    }
    __syncthreads();
  }
#pragma unroll
  for (int ii = 0; ii < 4; ii++) {
    int m = m0 + ty * 4 + ii;
    float sh = bias ? bias[m] : 0.f;
    bool dobn = (bng != nullptr);
    float bnsc = 0.f, bnsh = 0.f;
    if (dobn) {
      bnsc = bng[m] * rsqrtf(bnv[m] + 1e-5f);
      bnsh = bnb[m] - bnm[m] * bnsc;
    }
#pragma unroll
    for (int jj = 0; jj < 4; jj++) {
      int n = n0 + tx * 4 + jj;
      float v = acc[ii][jj] + sh;
      if (dobn) v = fmaxf(v * bnsc + bnsh, 0.f);
      if (Res) v += Res[(long long)b * srB + (long long)m * N + n];
      if (Ybf)
        Ybf[(long long)b * syB + (long long)m * N + n] = f2bf(v);
      else
        Y[(long long)b * syB + (long long)m * N + n] = v;
    }
  }
}

// Y[b,m,n] = epi( sum_k W[m,k]*(X[b,k,n]+Xadd) ) via split-bf16 MFMA (3 products).
__global__ __launch_bounds__(256) void gemm_mfma(
    const unsigned short* __restrict__ Whi, const unsigned short* __restrict__ Wlo,
    const float* __restrict__ X, long long sxB,
    const float* __restrict__ Xadd, long long saB,
    const float* __restrict__ bias,
    const float* __restrict__ bng, const float* __restrict__ bnb,
    const float* __restrict__ bnm, const float* __restrict__ bnv,
    const float* __restrict__ Res, long long srB,
    float* __restrict__ Y, unsigned short* __restrict__ Ybf, long long syB) {
  const int N = N_DIM, K = C_DIM;
  int b = blockIdx.z;
  int m0 = blockIdx.y * 128;
  int n0 = blockIdx.x * 64;
  int t = threadIdx.x;
  int w = t >> 6, l = t & 63;
  int lr = l & 15, lk = l >> 4;
  int j = t & 63, dq = t >> 6;   // B staging: col j, k-16-group dq
  int ar = t >> 3, as_ = t & 7;  // A staging: row-slot, k-octet

  __shared__ __align__(16) char Ah[128 * 128];  // [128 m][64 k] bf16, swizzled
  __shared__ __align__(16) char Al[128 * 128];
  __shared__ __align__(16) char Bh[64 * 128];  // [64 n][64 k] bf16, swizzled
  __shared__ __align__(16) char Bl[64 * 128];

  const float* Xb = X + (long long)b * sxB;
  const float* Adb = Xadd ? Xadd + (long long)b * saB : nullptr;

  f32x4 acc[2][4];
#pragma unroll
  for (int i = 0; i < 2; i++)
#pragma unroll
    for (int jq = 0; jq < 4; jq++) acc[i][jq] = f32x4{0.f, 0.f, 0.f, 0.f};

  for (int k0 = 0; k0 < K; k0 += 64) {
    // A: Whi/Wlo rows m0..m0+128, k-slice (coalesced short8)
    short8 wh[4], wl[4];
#pragma unroll
    for (int it = 0; it < 4; it++) {
      int r = it * 32 + ar;
      wh[it] = *(const short8*)(Whi + (long long)(m0 + r) * K + k0 + as_ * 8);
      wl[it] = *(const short8*)(Wlo + (long long)(m0 + r) * K + k0 + as_ * 8);
    }
    // B: X[k0+dq*16..+16][n0+j] (+Xadd), transpose + split
    float v[16];
#pragma unroll
    for (int i = 0; i < 16; i++) {
      float x = Xb[(long long)(k0 + dq * 16 + i) * N + n0 + j];
      if (Adb) x += Adb[(long long)(k0 + dq * 16 + i) * N + n0 + j];
      v[i] = x;
    }
    unsigned int ph[8], pl[8];
#pragma unroll
    for (int i = 0; i < 8; i++) {
      unsigned short h0 = f2bf(v[2 * i]), h1 = f2bf(v[2 * i + 1]);
      unsigned short l0 = f2bf(v[2 * i] - bf2f(h0)), l1 = f2bf(v[2 * i + 1] - bf2f(h1));
      ph[i] = (unsigned int)h0 | ((unsigned int)h1 << 16);
      pl[i] = (unsigned int)l0 | ((unsigned int)l1 << 16);
    }
    // LDS writes
#pragma unroll
    for (int it = 0; it < 4; it++) {
      int r = it * 32 + ar;
      *(short8*)(Ah + r * 128 + ((as_ ^ (r & 7)) << 4)) = wh[it];
      *(short8*)(Al + r * 128 + ((as_ ^ (r & 7)) << 4)) = wl[it];
    }
    {
      int o0 = dq * 2, o1 = dq * 2 + 1;
      *(uint4*)(Bh + j * 128 + ((o0 ^ (j & 7)) << 4)) = make_uint4(ph[0], ph[1], ph[2], ph[3]);
      *(uint4*)(Bh + j * 128 + ((o1 ^ (j & 7)) << 4)) = make_uint4(ph[4], ph[5], ph[6], ph[7]);
      *(uint4*)(Bl + j * 128 + ((o0 ^ (j & 7)) << 4)) = make_uint4(pl[0], pl[1], pl[2], pl[3]);
      *(uint4*)(Bl + j * 128 + ((o1 ^ (j & 7)) << 4)) = make_uint4(pl[4], pl[5], pl[6], pl[7]);
    }
    __syncthreads();
    // compute: 2 sub-K of 32; products hi*hi + hi*lo + lo*hi
#pragma unroll
    for (int sub = 0; sub < 2; sub++) {
      short8 ah[2], al2[2], bh[4], bl[4];
#pragma unroll
      for (int mi = 0; mi < 2; mi++) {
        int ra = w * 32 + mi * 16 + lr;
        ah[mi] = *(const short8*)(Ah + ra * 128 + (((sub * 4 + lk) ^ (ra & 7)) << 4));
        al2[mi] = *(const short8*)(Al + ra * 128 + (((sub * 4 + lk) ^ (ra & 7)) << 4));
      }
#pragma unroll
      for (int ni = 0; ni < 4; ni++) {
        int rb = ni * 16 + lr;
        bh[ni] = *(const short8*)(Bh + rb * 128 + (((sub * 4 + lk) ^ (rb & 7)) << 4));
        bl[ni] = *(const short8*)(Bl + rb * 128 + (((sub * 4 + lk) ^ (rb & 7)) << 4));
      }
#pragma unroll
      for (int mi = 0; mi < 2; mi++)
#pragma unroll
        for (int ni = 0; ni < 4; ni++) {
          acc[mi][ni] = __builtin_amdgcn_mfma_f32_16x16x32_bf16(ah[mi], bh[ni], acc[mi][ni], 0, 0, 0);
          acc[mi][ni] = __builtin_amdgcn_mfma_f32_16x16x32_bf16(ah[mi], bl[ni], acc[mi][ni], 0, 0, 0);
          acc[mi][ni] = __builtin_amdgcn_mfma_f32_16x16x32_bf16(al2[mi], bh[ni], acc[mi][ni], 0, 0, 0);
        }
    }
    __syncthreads();
  }
  // epilogue
#pragma unroll
  for (int mi = 0; mi < 2; mi++) {
#pragma unroll
    for (int jj = 0; jj < 4; jj++) {
      int m = m0 + w * 32 + mi * 16 + lk * 4 + jj;
      float sh = bias ? bias[m] : 0.f;
      bool dobn = (bng != nullptr);
      float bnsc = 0.f, bnsh = 0.f;
      if (dobn) {
        bnsc = bng[m] * rsqrtf(bnv[m] + 1e-5f);
        bnsh = bnb[m] - bnm[m] * bnsc;
      }
#pragma unroll
      for (int ni = 0; ni < 4; ni++) {
        int n = n0 + ni * 16 + lr;
        float vv = acc[mi][ni][jj] + sh;
        if (dobn) vv = fmaxf(vv * bnsc + bnsh, 0.f);
        if (Res) vv += Res[(long long)b * srB + (long long)m * N + n];
        if (Ybf)
          Ybf[(long long)b * syB + (long long)m * N + n] = f2bf(vv);
        else
          Y[(long long)b * syB + (long long)m * N + n] = vv;
      }
    }
  }
}

// E[b,r,c] = sum_d q[b,d,r]*q[b,d,c] via split-bf16 MFMA. 64x64 tile, K=CQ=64.
// Also emits per-(row, c-tile) online-softmax partials (m_t, s_t) to Epart,
// layout [32 ctile][B*N] float2, so the full E re-read for row stats is avoided.
__global__ __launch_bounds__(256) void energy_mfma(const float* __restrict__ q,
                                                   float* __restrict__ E,
                                                   float2* __restrict__ Epart) {
  const int N = N_DIM;
  int b = blockIdx.z;
  int r0 = blockIdx.y * 64;
  int c0 = blockIdx.x * 64;
  int t = threadIdx.x;
  int w = t >> 6, l = t & 63;
  int lr = l & 15, lk = l >> 4;
  int j = t & 63, dq = t >> 6;

  __shared__ __align__(16) char Ah[64 * 128];
  __shared__ __align__(16) char Al[64 * 128];
  __shared__ __align__(16) char Bh[64 * 128];
  __shared__ __align__(16) char Bl[64 * 128];

  const float* qb = q + (long long)b * CQ * N;
  {
    float va[16], vb[16];
#pragma unroll
    for (int i = 0; i < 16; i++) {
      va[i] = qb[(long long)(dq * 16 + i) * N + r0 + j];
      vb[i] = qb[(long long)(dq * 16 + i) * N + c0 + j];
    }
    unsigned int pah[8], pal[8], pbh[8], pbl[8];
#pragma unroll
    for (int i = 0; i < 8; i++) {
      unsigned short h0 = f2bf(va[2 * i]), h1 = f2bf(va[2 * i + 1]);
      unsigned short l0 = f2bf(va[2 * i] - bf2f(h0)), l1 = f2bf(va[2 * i + 1] - bf2f(h1));
      pah[i] = (unsigned int)h0 | ((unsigned int)h1 << 16);
      pal[i] = (unsigned int)l0 | ((unsigned int)l1 << 16);
      unsigned short g0 = f2bf(vb[2 * i]), g1 = f2bf(vb[2 * i + 1]);
      unsigned short m0_ = f2bf(vb[2 * i] - bf2f(g0)), m1 = f2bf(vb[2 * i + 1] - bf2f(g1));
      pbh[i] = (unsigned int)g0 | ((unsigned int)g1 << 16);
      pbl[i] = (unsigned int)m0_ | ((unsigned int)m1 << 16);
    }
    int o0 = dq * 2, o1 = dq * 2 + 1;
    *(uint4*)(Ah + j * 128 + ((o0 ^ (j & 7)) << 4)) = make_uint4(pah[0], pah[1], pah[2], pah[3]);
    *(uint4*)(Ah + j * 128 + ((o1 ^ (j & 7)) << 4)) = make_uint4(pah[4], pah[5], pah[6], pah[7]);
    *(uint4*)(Al + j * 128 + ((o0 ^ (j & 7)) << 4)) = make_uint4(pal[0], pal[1], pal[2], pal[3]);
    *(uint4*)(Al + j * 128 + ((o1 ^ (j & 7)) << 4)) = make_uint4(pal[4], pal[5], pal[6], pal[7]);
    *(uint4*)(Bh + j * 128 + ((o0 ^ (j & 7)) << 4)) = make_uint4(pbh[0], pbh[1], pbh[2], pbh[3]);
    *(uint4*)(Bh + j * 128 + ((o1 ^ (j & 7)) << 4)) = make_uint4(pbh[4], pbh[5], pbh[6], pbh[7]);
    *(uint4*)(Bl + j * 128 + ((o0 ^ (j & 7)) << 4)) = make_uint4(pbl[0], pbl[1], pbl[2], pbl[3]);
    *(uint4*)(Bl + j * 128 + ((o1 ^ (j & 7)) << 4)) = make_uint4(pbl[4], pbl[5], pbl[6], pbl[7]);
  }
  __syncthreads();

  f32x4 acc[4];
#pragma unroll
  for (int i = 0; i < 4; i++) acc[i] = f32x4{0.f, 0.f, 0.f, 0.f};
#pragma unroll
  for (int sub = 0; sub < 2; sub++) {
    int ra = w * 16 + lr;
    short8 ah = *(const short8*)(Ah + ra * 128 + (((sub * 4 + lk) ^ (ra & 7)) << 4));
    short8 al = *(const short8*)(Al + ra * 128 + (((sub * 4 + lk) ^ (ra & 7)) << 4));
    short8 bh[4], bl[4];
#pragma unroll
    for (int ni = 0; ni < 4; ni++) {
      int rb = ni * 16 + lr;
      bh[ni] = *(const short8*)(Bh + rb * 128 + (((sub * 4 + lk) ^ (rb & 7)) << 4));
      bl[ni] = *(const short8*)(Bl + rb * 128 + (((sub * 4 + lk) ^ (rb & 7)) << 4));
    }
#pragma unroll
    for (int ni = 0; ni < 4; ni++) {
      acc[ni] = __builtin_amdgcn_mfma_f32_16x16x32_bf16(ah, bh[ni], acc[ni], 0, 0, 0);
      acc[ni] = __builtin_amdgcn_mfma_f32_16x16x32_bf16(ah, bl[ni], acc[ni], 0, 0, 0);
      acc[ni] = __builtin_amdgcn_mfma_f32_16x16x32_bf16(al, bh[ni], acc[ni], 0, 0, 0);
    }
  }
  long long base = (long long)b * N * N;
#pragma unroll
  for (int ni = 0; ni < 4; ni++)
#pragma unroll
    for (int jj = 0; jj < 4; jj++)
      E[base + (long long)(r0 + w * 16 + lk * 4 + jj) * N + c0 + ni * 16 + lr] = acc[ni][jj];

  // ---- per-row partial softmax stats over this 64-col tile ----
  const long long BNr = (long long)B_DIM * N_DIM;
#pragma unroll
  for (int jj = 0; jj < 4; jj++) {
    float m = fmaxf(fmaxf(acc[0][jj], acc[1][jj]), fmaxf(acc[2][jj], acc[3][jj]));
#pragma unroll
    for (int msk = 1; msk < 16; msk <<= 1) m = fmaxf(m, __shfl_xor(m, msk, 64));
    float s = 0.f;
#pragma unroll
    for (int ni = 0; ni < 4; ni++) s += __expf(acc[ni][jj] - m);
#pragma unroll
    for (int msk = 1; msk < 16; msk <<= 1) s += __shfl_xor(s, msk, 64);
    if (lr == 0) {
      long long row = (long long)b * N + r0 + w * 16 + lk * 4 + jj;
      Epart[(long long)(c0 >> 6) * BNr + row] = make_float2(m, s);
    }
  }
}

// combine 32 per-tile partials per row -> rmax, rinv
__global__ void rowstats2(const float2* __restrict__ Epart, float* __restrict__ rmax,
                          float* __restrict__ rinv) {
  const long long BNr = (long long)B_DIM * N_DIM;
  int rloc = threadIdx.x & 63, qd = threadIdx.x >> 6;
  long long row = (long long)blockIdx.x * 64 + rloc;
  float2 v[8];
  float m = -3.4e38f;
#pragma unroll
  for (int i = 0; i < 8; i++) {
    v[i] = Epart[(long long)(qd * 8 + i) * BNr + row];
    m = fmaxf(m, v[i].x);
  }
  float s = 0.f;
#pragma unroll
  for (int i = 0; i < 8; i++) s += v[i].y * __expf(v[i].x - m);
  __shared__ float sm[4][64], ss[4][64];
  sm[qd][rloc] = m;
  ss[qd][rloc] = s;
  __syncthreads();
  if (qd == 0) {
    float M = fmaxf(fmaxf(sm[0][rloc], sm[1][rloc]), fmaxf(sm[2][rloc], sm[3][rloc]));
    float S = ss[0][rloc] * __expf(sm[0][rloc] - M) + ss[1][rloc] * __expf(sm[1][rloc] - M) +
              ss[2][rloc] * __expf(sm[2][rloc] - M) + ss[3][rloc] * __expf(sm[3][rloc] - M);
    rmax[row] = M;
    rinv[row] = 1.0f / S;
  }
}

// D[b,c,n] = Hprev - (val @ att)/colsum; att built on the fly from E rows (symmetry).
// Block: full C (256 rows) x 32 output cols; 512 blocks = 2/CU for latency hiding.
__global__ __launch_bounds__(256) void pv_mfma(
    const unsigned short* __restrict__ valbf,
    const float* __restrict__ E,
    const float* __restrict__ rmax, const float* __restrict__ rinv,
    const float* __restrict__ Hprev, long long shB, float* __restrict__ D) {
  const int N = N_DIM;
  int b = blockIdx.z;
  int n0 = blockIdx.x * PV_BN;
  int t = threadIdx.x;
  int w = t >> 6, l = t & 63;
  int lr = l & 15, lk = l >> 4;
  int brow = t >> 3, bkq = t & 7;  // B-build: n-row (0..31), k-octet (0..7)
  int ar = t >> 3, as_ = t & 7;    // A-stage: c-row slot, k-octet

  __shared__ __align__(16) char As[C_DIM * PV_BK * 2];   // 32768 B
  __shared__ __align__(16) char Bs[PV_BN * PV_BK * 2];   // 4096 B
  __shared__ float csred[8][PV_BN];
  __shared__ float csfin[PV_BN];

  const unsigned short* vb = valbf + (long long)b * C_DIM * N;
  const float* Ebr = E + ((long long)b * N + n0 + brow) * N;
  const float* rm = rmax + (long long)b * N;
  const float* ri = rinv + (long long)b * N;

  f32x4 acc[4][2];
#pragma unroll
  for (int i = 0; i < 4; i++)
#pragma unroll
    for (int jq = 0; jq < 2; jq++) acc[i][jq] = f32x4{0.f, 0.f, 0.f, 0.f};
  float cs = 0.f;

  float4 ev[2], rv[2], iv[2];
#pragma unroll
  for (int it = 0; it < 2; it++) {
    int kl = bkq * 4 + it * 32;
    ev[it] = *(const float4*)(Ebr + kl);
    rv[it] = *(const float4*)(rm + kl);
    iv[it] = *(const float4*)(ri + kl);
  }

  for (int k0 = 0; k0 < N; k0 += PV_BK) {
    short8 areg[8];
#pragma unroll
    for (int it = 0; it < 8; it++) {
      int r = it * 32 + ar;
      areg[it] = *(const short8*)(vb + (long long)r * N + k0 + as_ * 8);
    }
#pragma unroll
    for (int it = 0; it < 2; it++) {
      int kl = bkq * 4 + it * 32;
      float a0 = __expf(ev[it].x - rv[it].x) * iv[it].x;
      float a1 = __expf(ev[it].y - rv[it].y) * iv[it].y;
      float a2 = __expf(ev[it].z - rv[it].z) * iv[it].z;
      float a3 = __expf(ev[it].w - rv[it].w) * iv[it].w;
      unsigned short u0 = f2bf(a0), u1 = f2bf(a1), u2 = f2bf(a2), u3 = f2bf(a3);
      cs += bf2f(u0) + bf2f(u1) + bf2f(u2) + bf2f(u3);
      uint2 pk;
      pk.x = (unsigned int)u0 | ((unsigned int)u1 << 16);
      pk.y = (unsigned int)u2 | ((unsigned int)u3 << 16);
      *(uint2*)(Bs + brow * 128 + ((((kl >> 3) ^ (brow & 7)) << 4) | ((kl & 7) * 2))) = pk;
    }
#pragma unroll
    for (int it = 0; it < 8; it++) {
      int r = it * 32 + ar;
      *(short8*)(As + r * 128 + ((as_ ^ (r & 7)) << 4)) = areg[it];
    }
    __syncthreads();
    if (k0 + PV_BK < N) {
      int kb = k0 + PV_BK;
#pragma unroll
      for (int it = 0; it < 2; it++) {
        int kl = bkq * 4 + it * 32;
        ev[it] = *(const float4*)(Ebr + kb + kl);
        rv[it] = *(const float4*)(rm + kb + kl);
        iv[it] = *(const float4*)(ri + kb + kl);
      }
    }
#pragma unroll
    for (int sub = 0; sub < 2; sub++) {
      short8 af[4], bq[2];
#pragma unroll
      for (int ni = 0; ni < 2; ni++) {
        int r = ni * 16 + lr;
        bq[ni] = *(const short8*)(Bs + r * 128 + (((sub * 4 + lk) ^ (r & 7)) << 4));
      }
#pragma unroll
      for (int mi = 0; mi < 4; mi++) {
        int r = w * 64 + mi * 16 + lr;
        af[mi] = *(const short8*)(As + r * 128 + (((sub * 4 + lk) ^ (r & 7)) << 4));
      }
#pragma unroll
      for (int mi = 0; mi < 4; mi++)
#pragma unroll
        for (int ni = 0; ni < 2; ni++)
          acc[mi][ni] =
              __builtin_amdgcn_mfma_f32_16x16x32_bf16(af[mi], bq[ni], acc[mi][ni], 0, 0, 0);
    }
    __syncthreads();
  }

  csred[bkq][brow] = cs;
  __syncthreads();
  if (t < PV_BN) {
    float s = 0.f;
#pragma unroll
    for (int i = 0; i < 8; i++) s += csred[i][t];
    csfin[t] = s;
  }
  __syncthreads();

  const float* Hb = Hprev + (long long)b * shB;
  float* Db = D + (long long)b * C_DIM * N;
#pragma unroll
  for (int mi = 0; mi < 4; mi++) {
#pragma unroll
    for (int ni = 0; ni < 2; ni++) {
#pragma unroll
      for (int jj = 0; jj < 4; jj++) {
        int cr = w * 64 + mi * 16 + lk * 4 + jj;
        int ml = ni * 16 + lr;
        float denom = 1e-9f + csfin[ml];
        float xr = acc[mi][ni][jj] / denom;
        Db[(long long)cr * N + n0 + ml] = Hb[(long long)cr * N + n0 + ml] - xr;
      }
    }
  }
}

extern "C" void kernel_launch(void* const* d_in, const int* in_sizes, int n_in,
                              void* d_out, int out_size, void* d_ws, size_t ws_size,
                              hipStream_t stream) {
  const float* x = (const float*)d_in[0];
  const float* xyz = (const float*)d_in[1];
  const float* conv1_w = (const float*)d_in[2];
  const float* convpos_w = (const float*)d_in[3];
  const float* bn1_g = (const float*)d_in[4];
  const float* bn1_b = (const float*)d_in[5];
  const float* bn1_m = (const float*)d_in[6];
  const float* bn1_v = (const float*)d_in[7];
  const float* Wqk = (const float*)d_in[8];   // [4,64,256]
  const float* Wv = (const float*)d_in[9];    // [4,256,256]
  const float* bv = (const float*)d_in[10];   // [4,256]
  const float* Wt = (const float*)d_in[11];   // [4,256,256]
  const float* bt = (const float*)d_in[12];   // [4,256]
  const float* bng = (const float*)d_in[13];
  const float* bnb = (const float*)d_in[14];
  const float* bnm = (const float*)d_in[15];
  const float* bnv = (const float*)d_in[16];
  float* out = (float*)d_out;

  const long long BCN = (long long)B_DIM * C_DIM * N_DIM;
  const long long CN = (long long)C_DIM * N_DIM;
  const long long BN = (long long)B_DIM * N_DIM;
  const int WSZ = C_DIM * C_DIM;  // 65536
  float* ws = (float*)d_ws;
  float* pos = ws;                                       // BCN
  float* h0 = pos + BCN;                                 // BCN
  float* qbuf = h0 + BCN;                                // B*CQ*N
  float* dbuf = qbuf + (long long)B_DIM * CQ * N_DIM;    // BCN
  float* rmax = dbuf + BCN;                              // B*N
  float* rinv = rmax + BN;                               // B*N
  unsigned short* valbf = (unsigned short*)(rinv + BN);  // BCN bf16
  unsigned short* whi = valbf + BCN;                     // 9*65536 bf16
  unsigned short* wlo = whi + 9 * WSZ;                   // 9*65536 bf16
  float2* Epart = (float2*)(wlo + 9 * WSZ);              // 32 * B*N float2 (4 MB)
  float* E = (float*)(Epart + 32 * BN);                  // B*N*N

  // whi/wlo layout: [0]=conv1, [1..4]=Wv_i, [5..8]=Wt_i
  unsigned short* c1hi = whi;
  unsigned short* c1lo = wlo;
  unsigned short* wvhi = whi + WSZ;
  unsigned short* wvlo = wlo + WSZ;
  unsigned short* wthi = whi + 5 * WSZ;
  unsigned short* wtlo = wlo + 5 * WSZ;

  dim3 blk(256);

  split_kernel<<<dim3(WSZ / 256), blk, 0, stream>>>(conv1_w, c1hi, c1lo, WSZ);
  split_kernel<<<dim3(4 * WSZ / 256), blk, 0, stream>>>(Wv, wvhi, wvlo, 4 * WSZ);
  split_kernel<<<dim3(4 * WSZ / 256), blk, 0, stream>>>(Wt, wthi, wtlo, 4 * WSZ);

  pos_kernel<<<dim3(N_DIM / 256, C_DIM, B_DIM), blk, 0, stream>>>(convpos_w, xyz, pos);

  // h0 = relu(bn1(conv1_w @ x))
  gemm_mfma<<<dim3(N_DIM / 64, 2, B_DIM), blk, 0, stream>>>(
      c1hi, c1lo, x, CN, nullptr, 0, nullptr,
      bn1_g, bn1_b, bn1_m, bn1_v, nullptr, 0, h0, nullptr, CN);

  for (int i = 0; i < 4; i++) {
    const float* hp = (i == 0) ? h0 : out + (long long)(i - 1) * CN;
    long long shp = (i == 0) ? CN : 4 * CN;

    // q = Wqk_i @ (h + pos)   (fp32 VALU, exact)
    gemm_wx<<<dim3(N_DIM / TN, CQ / TM, B_DIM), blk, 0, stream>>>(
        Wqk + (long long)i * CQ * C_DIM, hp, shp, pos, CN, nullptr,
        nullptr, nullptr, nullptr, nullptr, nullptr, 0,
        qbuf, nullptr, (long long)CQ * N_DIM, CQ, C_DIM);

    // val = Wv_i @ (h + pos) + bv_i  (split-bf16 MFMA, bf16 out)
    gemm_mfma<<<dim3(N_DIM / 64, 2, B_DIM), blk, 0, stream>>>(
        wvhi + (long long)i * WSZ, wvlo + (long long)i * WSZ, hp, shp, pos, CN,
        bv + i * C_DIM, nullptr, nullptr, nullptr, nullptr, nullptr, 0,
        nullptr, valbf, CN);

    // E = q^T q  + per-tile softmax partials
    energy_mfma<<<dim3(N_DIM / 64, N_DIM / 64, B_DIM), blk, 0, stream>>>(qbuf, E, Epart);

    // combine partials -> row stats
    rowstats2<<<dim3(B_DIM * N_DIM / 64), blk, 0, stream>>>(Epart, rmax, rinv);

    // D = h - (val @ att)/colsum, att built on the fly (bf16 MFMA)
    pv_mfma<<<dim3(N_DIM / PV_BN, 1, B_DIM), blk, 0, stream>>>(
        valbf, E, rmax, rinv, hp, shp, dbuf);

    // out_i = h + relu(bn_i(Wt_i @ d + bt_i))  (split-bf16 MFMA)
    gemm_mfma<<<dim3(N_DIM / 64, 2, B_DIM), blk, 0, stream>>>(
        wthi + (long long)i * WSZ, wtlo + (long long)i * WSZ, dbuf, CN, nullptr, 0,
        bt + i * C_DIM, bng + i * C_DIM, bnb + i * C_DIM, bnm + i * C_DIM, bnv + i * C_DIM,
        hp, shp, out + (long long)i * CN, nullptr, 4 * CN);
  }
}